// Round 12
// baseline (176.799 us; speedup 1.0000x reference)
//
#include <hip/hip_runtime.h>
#include <math.h>

#define DF 128      // feature dim
#define TILE 4096   // edges per scatter block (LDS edge cache)
#define CAPA 8192   // bucket capacity, node side (mean 4081)
#define CAPB 10240  // bucket capacity, hyperedge side (mean 5096)
typedef unsigned int uint;
typedef __attribute__((ext_vector_type(8))) short bf16x8;
typedef __attribute__((ext_vector_type(4))) float f32x4;

__device__ __forceinline__ float leaky(float s){ return s > 0.f ? s : 0.2f*s; }

// f32 -> bf16 round-to-nearest-even, packed pair
__device__ __forceinline__ uint bfr(float f){
    uint u = __float_as_uint(f);
    return (u + 0x7fffu + ((u >> 16) & 1u)) >> 16;
}
__device__ __forceinline__ uint bf2(float a, float b){ return bfr(a) | (bfr(b) << 16); }
__device__ __forceinline__ float blo(uint v){ return __uint_as_float(v << 16); }
__device__ __forceinline__ float bhi(uint v){ return __uint_as_float(v & 0xffff0000u); }

// orderable-uint encoding for float atomicMax
__device__ __forceinline__ uint fenc(float f){
    uint u = __float_as_uint(f);
    return (u & 0x80000000u) ? ~u : (u | 0x80000000u);
}
__device__ __forceinline__ float fdec(uint k){
    return (k & 0x80000000u) ? __uint_as_float(k ^ 0x80000000u) : __uint_as_float(~k);
}

__device__ __forceinline__ void load_edge(const void* raw, int is64, int E, int e,
                                          int& n, int& m){
    if (is64){
        const long long* p = (const long long*)raw;
        n = (int)p[e]; m = (int)p[(long long)E + e];
    } else {
        const int* p = (const int*)raw;
        n = p[e]; m = p[E + e];
    }
}

// ---------------------------------------------------------------------------
// prep: b0 = int64 flag + bucket cursors + ctrl init ; b1,b2 = matvecs ;
// b3..b10 = W1t bf16 transpose.
__global__ __launch_bounds__(256) void prep(
        const uint* __restrict__ raw, int* __restrict__ ctrl,
        int* __restrict__ gcurA, int* __restrict__ gcurB,
        const float* __restrict__ W1, const float* __restrict__ W2,
        const float* __restrict__ W3,
        const float* __restrict__ att, const float* __restrict__ att2,
        float* __restrict__ w2a, float* __restrict__ v1,
        float* __restrict__ v2, float* __restrict__ v3,
        uint* __restrict__ W1t, int E)
{
    int t = threadIdx.x;
    int bid = blockIdx.x;
    if (bid == 0){
        __shared__ int cnt;
        gcurA[t] = t*CAPA;
        gcurB[t] = t*CAPB;
        if (t == 0){ cnt = 0; ctrl[1] = 0; ctrl[2] = 0; ctrl[3] = 0; }
        __syncthreads();
        int nz = 0;
        for (int i = 0; i < 4; i++){
            int w = 2*(t*4 + i) + 1;    // odd (high) words, int64 => all zero
            if (w < 2*E) nz += (raw[w] != 0u);
        }
        atomicAdd(&cnt, nz);
        __syncthreads();
        if (t == 0) ctrl[0] = (cnt == 0) ? 1 : 0;
    } else if (bid == 1){
        int d = t & 127;
        const float* W = (t < 128) ? W2 : W1;
        const float* a = (t < 128) ? (att + 128) : att;
        float s = 0.f;
        for (int f = 0; f < 128; f++) s += W[d*128 + f]*a[f];
        if (t < 128) w2a[d] = s; else v1[d] = s;
    } else if (bid == 2){
        __shared__ float sw3a[128];
        int d = t & 127;
        const float* W = (t < 128) ? W1 : W3;
        const float* a = (t < 128) ? att2 : (att2 + 128);
        float s = 0.f;
        for (int f = 0; f < 128; f++) s += W[d*128 + f]*a[f];
        if (t < 128) v2[d] = s; else sw3a[d] = s;
        __syncthreads();
        if (t < 128){
            float s2 = 0.f;
            for (int f = 0; f < 128; f++) s2 += W1[t*128 + f]*sw3a[f];
            v3[t] = s2;
        }
    } else {
        int base = (bid - 3)*1024;
        for (int p = base + t; p < base + 1024; p += 256){
            int f = p >> 6, dh = p & 63;
            W1t[p] = bf2(W1[(2*dh)*128 + f], W1[(2*dh + 1)*128 + f]);
        }
    }
}

// ---------------------------------------------------------------------------
// FUSED: blocks [0,SC) = multisplit scatter (LDS edge cache, 1 global edge
// read) ; blocks [SC,SC+GB) = MFMA gemm. 512 threads, 72KB LDS union.
__global__ __launch_bounds__(512) void scatter_gemm(
        const void* __restrict__ raw, const int* __restrict__ ctrl,
        int* __restrict__ gcurA, int* __restrict__ gcurB,
        uint* __restrict__ bktA, uint* __restrict__ bktB,
        const float* __restrict__ X, const uint* __restrict__ W1t,
        const float* __restrict__ w2a, const float* __restrict__ v1,
        const float* __restrict__ v2, const float* __restrict__ v3,
        uint* __restrict__ xlb, float* __restrict__ a1x, float* __restrict__ a2x,
        float* __restrict__ px, float* __restrict__ pxl,
        int E, int N, int SC)
{
    __shared__ char smem[73728];        // 72 KB
    int t = threadIdx.x;
    int bid = blockIdx.x;

    if (bid < SC){
        // ---------------- multisplit scatter ----------------
        uint* edges = (uint*)smem;               // 16 KB, packed (n<<14)|m
        uint* stA   = (uint*)(smem + 16384);     // 16 KB
        uint* stB   = (uint*)(smem + 32768);     // 16 KB
        int*  hA  = (int*)(smem + 49152);
        int*  scA = hA + 256; int* cuA = hA + 512; int* bA = hA + 768;
        int*  hB  = hA + 1024; int* scB = hA + 1280; int* cuB = hA + 1536; int* bB = hA + 1792;
        if (t < 256){ hA[t] = 0; hB[t] = 0; }
        __syncthreads();
        int tb = bid*TILE;
        int cnt = min(TILE, E - tb);
        int is64 = ctrl[0];
        // single global read: pack + count
        for (int i = t; i < cnt; i += 512){
            int n, m; load_edge(raw, is64, E, tb + i, n, m);
            uint v = ((uint)n << 14) | (uint)m;
            edges[i] = v;
            atomicAdd(&hA[n >> 8], 1);
            atomicAdd(&hB[m >> 6], 1);
        }
        __syncthreads();
        if (t < 256){ scA[t] = hA[t]; scB[t] = hB[t]; }
        __syncthreads();
        for (int off = 1; off < 256; off <<= 1){
            int vA = 0, vB = 0;
            if (t < 256 && t >= off){ vA = scA[t - off]; vB = scB[t - off]; }
            __syncthreads();
            if (t < 256){ scA[t] += vA; scB[t] += vB; }
            __syncthreads();
        }
        if (t < 256){
            scA[t] -= hA[t]; scB[t] -= hB[t];
            cuA[t] = scA[t]; cuB[t] = scB[t];
            bA[t] = atomicAdd(&gcurA[t], hA[t]);
            bB[t] = atomicAdd(&gcurB[t], hB[t]);
        }
        __syncthreads();
        // stage grouped by bucket (from LDS edge cache)
        for (int i = t; i < cnt; i += 512){
            uint v = edges[i];
            int n = (int)(v >> 14), m = (int)(v & 0x3FFFu);
            int pA = atomicAdd(&cuA[n >> 8], 1);
            stA[pA] = v;
            int pB = atomicAdd(&cuB[m >> 6], 1);
            stB[pB] = ((uint)m << 16) | (uint)n;
        }
        __syncthreads();
        // contiguous chunk writes
        for (int p = t; p < cnt; p += 512){
            uint v = stA[p]; int b = (int)(v >> 22);
            bktA[bA[b] + (p - scA[b])] = v;
            uint w = stB[p]; int c = (int)(w >> 22);
            bktB[bB[c] + (p - scB[c])] = w;
        }
    } else {
        // ---------------- gemm: 128 rows, 8 waves ----------------
        char* lds = smem;                        // A: 32 KB ; Bt at +32768: 32 KB
        int lane = t & 63, wv = t >> 6;
        int row0 = (bid - SC)*128;
        {   // stage Bt swizzled
            const uint4* g = (const uint4*)W1t;
            #pragma unroll
            for (int i = 0; i < 4; i++){
                int u = i*512 + t;
                int col = u >> 4;
                uint4 v = g[u];
                *(uint4*)(lds + 32768 + ((u*16) ^ ((col & 7) << 4))) = v;
            }
        }
        {   // stage A (f32->bf16) + exact f32 row dots
            int cg = t & 31;
            float4 c_px = ((const float4*)w2a)[cg];
            float4 c_a1 = ((const float4*)v1 )[cg];
            float4 c_a2 = ((const float4*)v2 )[cg];
            float4 c_pl = ((const float4*)v3 )[cg];
            #pragma unroll
            for (int i = 0; i < 8; i++){
                int idx = i*512 + t;
                int rl = idx >> 5;
                int row = row0 + rl;
                float4 xv = make_float4(0.f, 0.f, 0.f, 0.f);
                if (row < N) xv = ((const float4*)X)[(size_t)row*32 + cg];
                uint2 pk; pk.x = bf2(xv.x, xv.y); pk.y = bf2(xv.z, xv.w);
                *(uint2*)(lds + rl*256 + ((cg*8) ^ ((rl & 7) << 4))) = pk;
                float d0 = xv.x*c_px.x + xv.y*c_px.y + xv.z*c_px.z + xv.w*c_px.w;
                float d1 = xv.x*c_a1.x + xv.y*c_a1.y + xv.z*c_a1.z + xv.w*c_a1.w;
                float d2 = xv.x*c_a2.x + xv.y*c_a2.y + xv.z*c_a2.z + xv.w*c_a2.w;
                float d3 = xv.x*c_pl.x + xv.y*c_pl.y + xv.z*c_pl.z + xv.w*c_pl.w;
                #pragma unroll
                for (int off = 16; off > 0; off >>= 1){
                    d0 += __shfl_xor(d0, off); d1 += __shfl_xor(d1, off);
                    d2 += __shfl_xor(d2, off); d3 += __shfl_xor(d3, off);
                }
                if (cg == 0 && row < N){
                    px[row] = d0; a1x[row] = d1; a2x[row] = d2; pxl[row] = d3;
                }
            }
        }
        __syncthreads();
        f32x4 acc[8];
        #pragma unroll
        for (int i = 0; i < 8; i++) acc[i] = (f32x4){0.f, 0.f, 0.f, 0.f};
        int arow = wv*16 + (lane & 15);
        int aswz = (arow & 7) << 4;
        int bswz = (lane & 7) << 4;
        #pragma unroll
        for (int ks = 0; ks < 4; ks++){
            int au16 = ((lane >> 4) + ks*4)*16;
            bf16x8 af = *(const bf16x8*)(lds + arow*256 + (au16 ^ aswz));
            #pragma unroll
            for (int nf = 0; nf < 8; nf++){
                int bcol = nf*16 + (lane & 15);
                bf16x8 bf = *(const bf16x8*)(lds + 32768 + bcol*256 + (au16 ^ bswz));
                acc[nf] = __builtin_amdgcn_mfma_f32_16x16x32_bf16(af, bf, acc[nf], 0, 0, 0);
            }
        }
        __syncthreads();
        #pragma unroll
        for (int nf = 0; nf < 8; nf++){
            #pragma unroll
            for (int reg = 0; reg < 4; reg++){
                int rl = wv*16 + (lane >> 4)*4 + reg;
                int col = nf*16 + (lane & 15);
                *(unsigned short*)(lds + rl*256 + ((col*2) ^ ((rl & 7) << 4))) =
                    (unsigned short)bfr(acc[nf][reg]);
            }
        }
        __syncthreads();
        #pragma unroll
        for (int j = 0; j < 4; j++){
            int unit = j*64 + lane;
            int rl = wv*16 + (unit >> 4);
            int uu = unit & 15;
            uint4 v = *(const uint4*)(lds + rl*256 + ((uu*16) ^ ((rl & 7) << 4)));
            int grow = row0 + rl;
            if (grow < N) ((uint4*)xlb)[(size_t)grow*16 + uu] = v;
        }
    }
}

// ---------------------------------------------------------------------------
// csr_both: blocks [0,nbB) = hyperedge-side regroup + a1h + G1 (then ticket++);
// blocks [nbB, nbB+nbA) = node-side regroup + G2 bound, SPIN on ticket, then
// round-1 stats (needs a1h/g1key). All 353 blocks co-resident (35KB LDS,
// 4 waves) => spin is deadlock-free.
__global__ __launch_bounds__(256) void csr_both(
        const uint* __restrict__ bktB, const int* __restrict__ gcurB,
        int* __restrict__ adj1, int2* __restrict__ rg1,
        const float* __restrict__ px, float* __restrict__ a1h,
        uint* __restrict__ g1key,
        const uint* __restrict__ bktA, const int* __restrict__ gcurA,
        int* __restrict__ adj0, int2* __restrict__ rg0,
        const float* __restrict__ a1x, const float* __restrict__ hw,
        const float* __restrict__ pxl, uint* __restrict__ g2key,
        float4* __restrict__ pk1, float* __restrict__ Dinv,
        int* __restrict__ ticket, int N, int M, int nbB)
{
    __shared__ int h[256], sc[256], cu[256];
    __shared__ uint sm[CAPA];           // 32 KB
    __shared__ float fsum[64];
    __shared__ float wmax[4];
    int t = threadIdx.x;

    if (blockIdx.x < nbB){
        // ---------------- hyperedge side ----------------
        int b = blockIdx.x;
        int sb = b*CAPB;
        int total = gcurB[b] - sb;
        int kb = b << 6;
        if (t < 64){ h[t] = 0; fsum[t] = 0.f; }
        __syncthreads();
        const uint* src = bktB + sb;
        for (int i = t; i < total; i += 256)
            atomicAdd(&h[(int)(src[i] >> 16) - kb], 1);
        __syncthreads();
        if (t < 64) sc[t] = h[t];
        __syncthreads();
        for (int off = 1; off < 64; off <<= 1){
            int v = (t < 64 && t >= off) ? sc[t - off] : 0;
            __syncthreads();
            if (t < 64) sc[t] += v;
            __syncthreads();
        }
        if (t < 64){ sc[t] -= h[t]; cu[t] = sc[t]; }
        __syncthreads();
        for (int i = t; i < total; i += 256){
            uint v = src[i];
            int k = (int)(v >> 16) - kb;
            int pos = atomicAdd(&cu[k], 1);
            int n = (int)(v & 0xFFFFu);
            adj1[sb + pos] = n;
            atomicAdd(&fsum[k], px[n]);
        }
        __syncthreads();
        if (t < 64){
            int key = kb + t;
            float av = -3.4e38f;
            if (key < M){
                av = (h[t] > 0) ? fsum[t]/(float)h[t] : 0.f;
                rg1[key] = make_int2(sb + sc[t], sb + sc[t] + h[t]);
                a1h[key] = av;
            }
            #pragma unroll
            for (int off = 32; off > 0; off >>= 1)
                av = fmaxf(av, __shfl_xor(av, off));
            if (t == 0) atomicMax(g1key, fenc(av));
        }
        // release: a1h/rg1/adj1/g1key visible, then count up
        __threadfence();
        __syncthreads();
        if (t == 0) atomicAdd(ticket, 1);
    } else {
        // ---------------- node side ----------------
        int b = blockIdx.x - nbB;
        int sb = b*CAPA;
        int total = gcurA[b] - sb;
        int kb = b << 8;
        h[t] = 0;
        __syncthreads();
        const uint* src = bktA + sb;
        for (int i = t; i < total; i += 256)
            atomicAdd(&h[(int)(src[i] >> 14) - kb], 1);
        __syncthreads();
        sc[t] = h[t];
        __syncthreads();
        for (int off = 1; off < 256; off <<= 1){
            int v = (t >= off) ? sc[t - off] : 0;
            __syncthreads();
            sc[t] += v;
            __syncthreads();
        }
        sc[t] -= h[t];
        cu[t] = sc[t];
        __syncthreads();
        for (int i = t; i < total; i += 256){
            uint v = src[i];
            int k = (int)(v >> 14) - kb;
            int pos = atomicAdd(&cu[k], 1);
            sm[pos] = v & 0x3FFFu;
        }
        __syncthreads();
        for (int i = t; i < total; i += 256) adj0[sb + i] = (int)sm[i];
        int key = kb + t;
        int deg = h[t], beg = sc[t];
        if (key < N) rg0[key] = make_int2(sb + beg, sb + beg + deg);
        float pl = (key < N) ? pxl[key] : 0.f;
        // G2 bound: a2h is an alpha-weighted mean of pxl => bounded by max pxl
        float pv = pl;
        #pragma unroll
        for (int off = 32; off > 0; off >>= 1) pv = fmaxf(pv, __shfl_xor(pv, off));
        if ((t & 63) == 0) wmax[t >> 6] = pv;
        __syncthreads();
        if (t == 0){
            float bm = fmaxf(fmaxf(wmax[0], wmax[1]), fmaxf(wmax[2], wmax[3]));
            atomicMax(g2key, fenc(fmaxf(bm, 0.f)));
        }
        // acquire: wait for all hyperedge-side blocks
        if (t == 0){
            while (atomicAdd(ticket, 0) < nbB) __builtin_amdgcn_s_sleep(2);
        }
        __syncthreads();
        __threadfence();    // invalidate L1; a1h/g1key reads below see L2
        float G1 = fdec((uint)atomicAdd((int*)g1key, 0));
        if (key < N){
            float ax = a1x[key];
            float mx = leaky(ax + G1);      // upper bound (leaky monotonic)
            float se = 0.f, wsum = 0.f;
            for (int j = 0; j < deg; j++){
                int m = (int)sm[beg + j];
                wsum += hw[m];
                se += expf(leaky(ax + a1h[m]) - mx);
            }
            pk1[key] = make_float4(ax, mx, (deg > 0) ? 1.f/se : 0.f, pl);
            Dinv[key] = (wsum > 0.f) ? 1.f/wsum : 0.f;
        }
    }
}

// ---------------------------------------------------------------------------
// out_e (bf16): one wave per hyperedge; 8 edge-rows in flight. NO atomics.
__global__ __launch_bounds__(256) void agg_oute(
    const int2* __restrict__ rg1, const int* __restrict__ adj1,
    const float4* __restrict__ pk1, const float* __restrict__ a1h,
    const uint* __restrict__ xlb, uint* __restrict__ outeb,
    float* __restrict__ a2h, int M)
{
    int m = blockIdx.x*4 + (threadIdx.x >> 6);
    int lane = threadIdx.x & 63;
    if (m >= M) return;
    int2 r = rg1[m];
    int b = r.x, e = r.y, deg = e - b;
    float binv = deg > 0 ? 1.f/(float)deg : 0.f;
    float ah = a1h[m];
    int sub = lane >> 4, cg = lane & 15;
    const uint4* x4p = (const uint4*)xlb;
    float acc[8] = {0,0,0,0,0,0,0,0};
    float sca = 0.f;
    for (int base = b; base < e; base += 64){
        int cnt = min(64, e - base);
        int n = 0; float al = 0.f;
        if (lane < cnt){
            n = adj1[base + lane];
            float4 g = pk1[n];                 // (a1x, mx1, is1, pxl)
            al = expf(leaky(g.x + ah) - g.y) * g.z;
            sca += al * g.w;
        }
        int t4 = 0;
        for (; t4 + 8 <= cnt; t4 += 8){
            int   nb0 = __shfl(n,  t4 + sub);
            float ab0 = __shfl(al, t4 + sub);
            int   nb1 = __shfl(n,  t4 + 4 + sub);
            float ab1 = __shfl(al, t4 + 4 + sub);
            uint4 v0 = x4p[(size_t)nb0*16 + cg];
            uint4 v1 = x4p[(size_t)nb1*16 + cg];
            acc[0] += ab0*blo(v0.x); acc[1] += ab0*bhi(v0.x);
            acc[2] += ab0*blo(v0.y); acc[3] += ab0*bhi(v0.y);
            acc[4] += ab0*blo(v0.z); acc[5] += ab0*bhi(v0.z);
            acc[6] += ab0*blo(v0.w); acc[7] += ab0*bhi(v0.w);
            acc[0] += ab1*blo(v1.x); acc[1] += ab1*bhi(v1.x);
            acc[2] += ab1*blo(v1.y); acc[3] += ab1*bhi(v1.y);
            acc[4] += ab1*blo(v1.z); acc[5] += ab1*bhi(v1.z);
            acc[6] += ab1*blo(v1.w); acc[7] += ab1*bhi(v1.w);
        }
        for (; t4 < cnt; t4 += 4){
            int   nb = __shfl(n,  t4 + sub);   // al=0 for tail lanes -> no-op
            float ab = __shfl(al, t4 + sub);
            uint4 v = x4p[(size_t)nb*16 + cg];
            acc[0] += ab*blo(v.x); acc[1] += ab*bhi(v.x);
            acc[2] += ab*blo(v.y); acc[3] += ab*bhi(v.y);
            acc[4] += ab*blo(v.z); acc[5] += ab*bhi(v.z);
            acc[6] += ab*blo(v.w); acc[7] += ab*bhi(v.w);
        }
    }
    #pragma unroll
    for (int i = 0; i < 8; i++){
        acc[i] += __shfl_xor(acc[i], 32);
        acc[i] += __shfl_xor(acc[i], 16);
    }
    #pragma unroll
    for (int off = 32; off > 0; off >>= 1) sca += __shfl_xor(sca, off);
    if (lane < 16){
        uint4 w;
        w.x = bf2(binv*acc[0], binv*acc[1]);
        w.y = bf2(binv*acc[2], binv*acc[3]);
        w.z = bf2(binv*acc[4], binv*acc[5]);
        w.w = bf2(binv*acc[6], binv*acc[7]);
        ((uint4*)outeb)[(size_t)m*16 + cg] = w;
    }
    if (lane == 0) a2h[m] = binv*sca;
}

// out[n] = Dinv/se * sum exp(..) * out_e[m] : one wave per node; stats fused,
// global-bound shift (no max pass).
__global__ __launch_bounds__(256) void agg_outn(
    const int2* __restrict__ rg0, const int* __restrict__ adj0,
    const float* __restrict__ a2x, const float* __restrict__ a2h,
    const float* __restrict__ Dinv, const uint* __restrict__ outeb,
    const uint* __restrict__ g2key, float* __restrict__ out, int N)
{
    int n = blockIdx.x*4 + (threadIdx.x >> 6);
    int lane = threadIdx.x & 63;
    if (n >= N) return;
    int2 r = rg0[n];
    int b = r.x, e = r.y;
    float ax = a2x[n];
    float mx = leaky(ax + fdec(*g2key));   // upper bound (leaky monotonic)
    int sub = lane >> 4, cg = lane & 15;
    const uint4* o4p = (const uint4*)outeb;
    float acc[8] = {0,0,0,0,0,0,0,0};
    float sa = 0.f;
    for (int base = b; base < e; base += 64){
        int cnt = min(64, e - base);
        int m = 0; float al = 0.f;
        if (lane < cnt){
            m = adj0[base + lane];
            al = expf(leaky(ax + a2h[m]) - mx);
            sa += al;
        }
        int t4 = 0;
        for (; t4 + 8 <= cnt; t4 += 8){
            int   mb0 = __shfl(m,  t4 + sub);
            float ab0 = __shfl(al, t4 + sub);
            int   mb1 = __shfl(m,  t4 + 4 + sub);
            float ab1 = __shfl(al, t4 + 4 + sub);
            uint4 v0 = o4p[(size_t)mb0*16 + cg];
            uint4 v1 = o4p[(size_t)mb1*16 + cg];
            acc[0] += ab0*blo(v0.x); acc[1] += ab0*bhi(v0.x);
            acc[2] += ab0*blo(v0.y); acc[3] += ab0*bhi(v0.y);
            acc[4] += ab0*blo(v0.z); acc[5] += ab0*bhi(v0.z);
            acc[6] += ab0*blo(v0.w); acc[7] += ab0*bhi(v0.w);
            acc[0] += ab1*blo(v1.x); acc[1] += ab1*bhi(v1.x);
            acc[2] += ab1*blo(v1.y); acc[3] += ab1*bhi(v1.y);
            acc[4] += ab1*blo(v1.z); acc[5] += ab1*bhi(v1.z);
            acc[6] += ab1*blo(v1.w); acc[7] += ab1*bhi(v1.w);
        }
        for (; t4 < cnt; t4 += 4){
            int   mb = __shfl(m,  t4 + sub);
            float ab = __shfl(al, t4 + sub);
            uint4 v = o4p[(size_t)mb*16 + cg];
            acc[0] += ab*blo(v.x); acc[1] += ab*bhi(v.x);
            acc[2] += ab*blo(v.y); acc[3] += ab*bhi(v.y);
            acc[4] += ab*blo(v.z); acc[5] += ab*bhi(v.z);
            acc[6] += ab*blo(v.w); acc[7] += ab*bhi(v.w);
        }
    }
    #pragma unroll
    for (int off = 32; off > 0; off >>= 1) sa += __shfl_xor(sa, off);
    #pragma unroll
    for (int i = 0; i < 8; i++){
        acc[i] += __shfl_xor(acc[i], 32);
        acc[i] += __shfl_xor(acc[i], 16);
    }
    float scale = (sa > 0.f) ? Dinv[n]/sa : 0.f;
    if (lane < 16){
        float4 o0 = make_float4(scale*acc[0], scale*acc[1], scale*acc[2], scale*acc[3]);
        float4 o1 = make_float4(scale*acc[4], scale*acc[5], scale*acc[6], scale*acc[7]);
        ((float4*)out)[(size_t)n*32 + cg*2]     = o0;
        ((float4*)out)[(size_t)n*32 + cg*2 + 1] = o1;
    }
}

// ---------------------------------------------------------------------------
extern "C" void kernel_launch(void* const* d_in, const int* in_sizes, int n_in,
                              void* d_out, int out_size, void* d_ws, size_t ws_size,
                              hipStream_t stream){
    const float* x    = (const float*)d_in[0];
    const void*  hidx = d_in[1];
    const float* hw   = (const float*)d_in[2];
    const float* W1   = (const float*)d_in[3];
    const float* W2   = (const float*)d_in[4];
    const float* W3   = (const float*)d_in[5];
    const float* att  = (const float*)d_in[6];
    const float* att2 = (const float*)d_in[7];
    float* out = (float*)d_out;

    const int N = in_sizes[0] / DF;
    const int E = in_sizes[1] / 2;
    const int M = in_sizes[2];

    char* ws = (char*)d_ws;
    size_t o = 0;
    auto take = [&](size_t bytes) -> char* {
        char* p = ws + o;
        o += (bytes + 255) & ~(size_t)255;
        return p;
    };
    const int nbA = (N + 255) >> 8;     // node-side buckets
    const int nbB = (M + 63) >> 6;      // hyperedge-side buckets

    uint*   xlb  = (uint*)  take((size_t)N*64*4);
    uint*   outeb= (uint*)  take((size_t)M*64*4);
    float*  a1x  = (float*) take((size_t)N*4);
    float*  a2x  = (float*) take((size_t)N*4);
    float*  px   = (float*) take((size_t)N*4);
    float*  pxl  = (float*) take((size_t)N*4);
    float*  Dinv = (float*) take((size_t)N*4);
    float*  a1h  = (float*) take((size_t)M*4);
    float*  a2h  = (float*) take((size_t)M*4);
    float4* pk1  = (float4*)take((size_t)N*16);
    float*  w2a  = (float*) take(DF*4);
    float*  v1   = (float*) take(DF*4);
    float*  v2   = (float*) take(DF*4);
    float*  v3   = (float*) take(DF*4);
    uint*   W1t  = (uint*)  take(128*64*4);
    int2*   rg0  = (int2*)  take((size_t)N*8);
    int2*   rg1  = (int2*)  take((size_t)M*8);
    int*    gcurA= (int*)   take(256*4);
    int*    gcurB= (int*)   take(256*4);
    uint*   bktA = (uint*)  take((size_t)nbA*CAPA*4 + TILE*4);
    uint*   bktB = (uint*)  take((size_t)nbB*CAPB*4 + TILE*4);
    int*    adj0 = (int*)   take((size_t)nbA*CAPA*4);
    int*    adj1 = (int*)   take((size_t)nbB*CAPB*4);
    int*    ctrl = (int*)   take(256);   // [0]=flag [1]=g1key [2]=g2key [3]=ticket

    const int SC = (E + TILE - 1)/TILE;
    const int GB = (N + 127)/128;

    // 1. flag + cursors + ctrl init + matvecs + W1t
    prep<<<11, 256, 0, stream>>>((const uint*)hidx, ctrl, gcurA, gcurB,
                                 W1, W2, W3, att, att2, w2a, v1, v2, v3, W1t, E);
    // 2. multisplit | MFMA gemm (fused, independent block ranges)
    scatter_gemm<<<SC + GB, 512, 0, stream>>>(hidx, ctrl, gcurA, gcurB,
                                 bktA, bktB, x, W1t, w2a, v1, v2, v3,
                                 xlb, a1x, a2x, px, pxl, E, N, SC);
    // 3. both CSR sides in one dispatch (ticket-ordered stats tail)
    csr_both<<<nbB + nbA, 256, 0, stream>>>(bktB, gcurB, adj1, rg1, px, a1h,
                                 (uint*)&ctrl[1],
                                 bktA, gcurA, adj0, rg0, a1x, hw, pxl,
                                 (uint*)&ctrl[2], pk1, Dinv, &ctrl[3],
                                 N, M, nbB);
    // 4. round-1 aggregation (no atomics)
    agg_oute<<<(M + 3)/4, 256, 0, stream>>>(rg1, adj1, pk1, a1h, xlb, outeb,
                                            a2h, M);
    // 5. round 2 (stats fused, bound shift)
    agg_outn<<<(N + 3)/4, 256, 0, stream>>>(rg0, adj0, a2x, a2h, Dinv, outeb,
                                            (uint*)&ctrl[2], out, N);
}

// Round 13
// 128.218 us; speedup vs baseline: 1.3789x; 1.3789x over previous
//
#include <hip/hip_runtime.h>
#include <math.h>

#define DF 128      // feature dim
#define TILE 4096   // edges per scatter block (LDS edge cache)
#define CAPA 8192   // bucket capacity, node side (mean 4081)
#define CAPB 10240  // bucket capacity, hyperedge side (mean 5096)
typedef unsigned int uint;
typedef __attribute__((ext_vector_type(8))) short bf16x8;
typedef __attribute__((ext_vector_type(4))) float f32x4;

__device__ __forceinline__ float leaky(float s){ return s > 0.f ? s : 0.2f*s; }

// f32 -> bf16 round-to-nearest-even, packed pair
__device__ __forceinline__ uint bfr(float f){
    uint u = __float_as_uint(f);
    return (u + 0x7fffu + ((u >> 16) & 1u)) >> 16;
}
__device__ __forceinline__ uint bf2(float a, float b){ return bfr(a) | (bfr(b) << 16); }
__device__ __forceinline__ float blo(uint v){ return __uint_as_float(v << 16); }
__device__ __forceinline__ float bhi(uint v){ return __uint_as_float(v & 0xffff0000u); }

// orderable-uint encoding for float atomicMax
__device__ __forceinline__ uint fenc(float f){
    uint u = __float_as_uint(f);
    return (u & 0x80000000u) ? ~u : (u | 0x80000000u);
}
__device__ __forceinline__ float fdec(uint k){
    return (k & 0x80000000u) ? __uint_as_float(k ^ 0x80000000u) : __uint_as_float(~k);
}

__device__ __forceinline__ void load_edge(const void* raw, int is64, int E, int e,
                                          int& n, int& m){
    if (is64){
        const long long* p = (const long long*)raw;
        n = (int)p[e]; m = (int)p[(long long)E + e];
    } else {
        const int* p = (const int*)raw;
        n = p[e]; m = p[E + e];
    }
}

// ---------------------------------------------------------------------------
// prep: b0 = int64 flag + bucket cursors + ctrl init ; b1,b2 = matvecs ;
// b3..b10 = W1t bf16 transpose.
__global__ __launch_bounds__(256) void prep(
        const uint* __restrict__ raw, int* __restrict__ ctrl,
        int* __restrict__ gcurA, int* __restrict__ gcurB,
        const float* __restrict__ W1, const float* __restrict__ W2,
        const float* __restrict__ W3,
        const float* __restrict__ att, const float* __restrict__ att2,
        float* __restrict__ w2a, float* __restrict__ v1,
        float* __restrict__ v2, float* __restrict__ v3,
        uint* __restrict__ W1t, int E)
{
    int t = threadIdx.x;
    int bid = blockIdx.x;
    if (bid == 0){
        __shared__ int cnt;
        gcurA[t] = t*CAPA;
        gcurB[t] = t*CAPB;
        if (t == 0){ cnt = 0; ctrl[1] = 0; ctrl[2] = 0; }   // g1key, g2key
        __syncthreads();
        int nz = 0;
        for (int i = 0; i < 4; i++){
            int w = 2*(t*4 + i) + 1;    // odd (high) words, int64 => all zero
            if (w < 2*E) nz += (raw[w] != 0u);
        }
        atomicAdd(&cnt, nz);
        __syncthreads();
        if (t == 0) ctrl[0] = (cnt == 0) ? 1 : 0;
    } else if (bid == 1){
        int d = t & 127;
        const float* W = (t < 128) ? W2 : W1;
        const float* a = (t < 128) ? (att + 128) : att;
        float s = 0.f;
        for (int f = 0; f < 128; f++) s += W[d*128 + f]*a[f];
        if (t < 128) w2a[d] = s; else v1[d] = s;
    } else if (bid == 2){
        __shared__ float sw3a[128];
        int d = t & 127;
        const float* W = (t < 128) ? W1 : W3;
        const float* a = (t < 128) ? att2 : (att2 + 128);
        float s = 0.f;
        for (int f = 0; f < 128; f++) s += W[d*128 + f]*a[f];
        if (t < 128) v2[d] = s; else sw3a[d] = s;
        __syncthreads();
        if (t < 128){
            float s2 = 0.f;
            for (int f = 0; f < 128; f++) s2 += W1[t*128 + f]*sw3a[f];
            v3[t] = s2;
        }
    } else {
        int base = (bid - 3)*1024;
        for (int p = base + t; p < base + 1024; p += 256){
            int f = p >> 6, dh = p & 63;
            W1t[p] = bf2(W1[(2*dh)*128 + f], W1[(2*dh + 1)*128 + f]);
        }
    }
}

// ---------------------------------------------------------------------------
// FUSED: blocks [0,SC) = multisplit scatter (LDS edge cache, 1 global edge
// read) ; blocks [SC,SC+GB) = MFMA gemm. 512 threads, 72KB LDS union.
__global__ __launch_bounds__(512) void scatter_gemm(
        const void* __restrict__ raw, const int* __restrict__ ctrl,
        int* __restrict__ gcurA, int* __restrict__ gcurB,
        uint* __restrict__ bktA, uint* __restrict__ bktB,
        const float* __restrict__ X, const uint* __restrict__ W1t,
        const float* __restrict__ w2a, const float* __restrict__ v1,
        const float* __restrict__ v2, const float* __restrict__ v3,
        uint* __restrict__ xlb, float* __restrict__ a1x, float* __restrict__ a2x,
        float* __restrict__ px, float* __restrict__ pxl,
        int E, int N, int SC)
{
    __shared__ char smem[73728];        // 72 KB
    int t = threadIdx.x;
    int bid = blockIdx.x;

    if (bid < SC){
        // ---------------- multisplit scatter ----------------
        uint* edges = (uint*)smem;               // 16 KB, packed (n<<14)|m
        uint* stA   = (uint*)(smem + 16384);     // 16 KB
        uint* stB   = (uint*)(smem + 32768);     // 16 KB
        int*  hA  = (int*)(smem + 49152);
        int*  scA = hA + 256; int* cuA = hA + 512; int* bA = hA + 768;
        int*  hB  = hA + 1024; int* scB = hA + 1280; int* cuB = hA + 1536; int* bB = hA + 1792;
        if (t < 256){ hA[t] = 0; hB[t] = 0; }
        __syncthreads();
        int tb = bid*TILE;
        int cnt = min(TILE, E - tb);
        int is64 = ctrl[0];
        // single global read: pack + count
        for (int i = t; i < cnt; i += 512){
            int n, m; load_edge(raw, is64, E, tb + i, n, m);
            uint v = ((uint)n << 14) | (uint)m;
            edges[i] = v;
            atomicAdd(&hA[n >> 8], 1);
            atomicAdd(&hB[m >> 6], 1);
        }
        __syncthreads();
        if (t < 256){ scA[t] = hA[t]; scB[t] = hB[t]; }
        __syncthreads();
        for (int off = 1; off < 256; off <<= 1){
            int vA = 0, vB = 0;
            if (t < 256 && t >= off){ vA = scA[t - off]; vB = scB[t - off]; }
            __syncthreads();
            if (t < 256){ scA[t] += vA; scB[t] += vB; }
            __syncthreads();
        }
        if (t < 256){
            scA[t] -= hA[t]; scB[t] -= hB[t];
            cuA[t] = scA[t]; cuB[t] = scB[t];
            bA[t] = atomicAdd(&gcurA[t], hA[t]);
            bB[t] = atomicAdd(&gcurB[t], hB[t]);
        }
        __syncthreads();
        // stage grouped by bucket (from LDS edge cache)
        for (int i = t; i < cnt; i += 512){
            uint v = edges[i];
            int n = (int)(v >> 14), m = (int)(v & 0x3FFFu);
            int pA = atomicAdd(&cuA[n >> 8], 1);
            stA[pA] = v;
            int pB = atomicAdd(&cuB[m >> 6], 1);
            stB[pB] = ((uint)m << 16) | (uint)n;
        }
        __syncthreads();
        // contiguous chunk writes
        for (int p = t; p < cnt; p += 512){
            uint v = stA[p]; int b = (int)(v >> 22);
            bktA[bA[b] + (p - scA[b])] = v;
            uint w = stB[p]; int c = (int)(w >> 22);
            bktB[bB[c] + (p - scB[c])] = w;
        }
    } else {
        // ---------------- gemm: 128 rows, 8 waves ----------------
        char* lds = smem;                        // A: 32 KB ; Bt at +32768: 32 KB
        int lane = t & 63, wv = t >> 6;
        int row0 = (bid - SC)*128;
        {   // stage Bt swizzled
            const uint4* g = (const uint4*)W1t;
            #pragma unroll
            for (int i = 0; i < 4; i++){
                int u = i*512 + t;
                int col = u >> 4;
                uint4 v = g[u];
                *(uint4*)(lds + 32768 + ((u*16) ^ ((col & 7) << 4))) = v;
            }
        }
        {   // stage A (f32->bf16) + exact f32 row dots
            int cg = t & 31;
            float4 c_px = ((const float4*)w2a)[cg];
            float4 c_a1 = ((const float4*)v1 )[cg];
            float4 c_a2 = ((const float4*)v2 )[cg];
            float4 c_pl = ((const float4*)v3 )[cg];
            #pragma unroll
            for (int i = 0; i < 8; i++){
                int idx = i*512 + t;
                int rl = idx >> 5;
                int row = row0 + rl;
                float4 xv = make_float4(0.f, 0.f, 0.f, 0.f);
                if (row < N) xv = ((const float4*)X)[(size_t)row*32 + cg];
                uint2 pk; pk.x = bf2(xv.x, xv.y); pk.y = bf2(xv.z, xv.w);
                *(uint2*)(lds + rl*256 + ((cg*8) ^ ((rl & 7) << 4))) = pk;
                float d0 = xv.x*c_px.x + xv.y*c_px.y + xv.z*c_px.z + xv.w*c_px.w;
                float d1 = xv.x*c_a1.x + xv.y*c_a1.y + xv.z*c_a1.z + xv.w*c_a1.w;
                float d2 = xv.x*c_a2.x + xv.y*c_a2.y + xv.z*c_a2.z + xv.w*c_a2.w;
                float d3 = xv.x*c_pl.x + xv.y*c_pl.y + xv.z*c_pl.z + xv.w*c_pl.w;
                #pragma unroll
                for (int off = 16; off > 0; off >>= 1){
                    d0 += __shfl_xor(d0, off); d1 += __shfl_xor(d1, off);
                    d2 += __shfl_xor(d2, off); d3 += __shfl_xor(d3, off);
                }
                if (cg == 0 && row < N){
                    px[row] = d0; a1x[row] = d1; a2x[row] = d2; pxl[row] = d3;
                }
            }
        }
        __syncthreads();
        f32x4 acc[8];
        #pragma unroll
        for (int i = 0; i < 8; i++) acc[i] = (f32x4){0.f, 0.f, 0.f, 0.f};
        int arow = wv*16 + (lane & 15);
        int aswz = (arow & 7) << 4;
        int bswz = (lane & 7) << 4;
        #pragma unroll
        for (int ks = 0; ks < 4; ks++){
            int au16 = ((lane >> 4) + ks*4)*16;
            bf16x8 af = *(const bf16x8*)(lds + arow*256 + (au16 ^ aswz));
            #pragma unroll
            for (int nf = 0; nf < 8; nf++){
                int bcol = nf*16 + (lane & 15);
                bf16x8 bf = *(const bf16x8*)(lds + 32768 + bcol*256 + (au16 ^ bswz));
                acc[nf] = __builtin_amdgcn_mfma_f32_16x16x32_bf16(af, bf, acc[nf], 0, 0, 0);
            }
        }
        __syncthreads();
        #pragma unroll
        for (int nf = 0; nf < 8; nf++){
            #pragma unroll
            for (int reg = 0; reg < 4; reg++){
                int rl = wv*16 + (lane >> 4)*4 + reg;
                int col = nf*16 + (lane & 15);
                *(unsigned short*)(lds + rl*256 + ((col*2) ^ ((rl & 7) << 4))) =
                    (unsigned short)bfr(acc[nf][reg]);
            }
        }
        __syncthreads();
        #pragma unroll
        for (int j = 0; j < 4; j++){
            int unit = j*64 + lane;
            int rl = wv*16 + (unit >> 4);
            int uu = unit & 15;
            uint4 v = *(const uint4*)(lds + rl*256 + ((uu*16) ^ ((rl & 7) << 4)));
            int grow = row0 + rl;
            if (grow < N) ((uint4*)xlb)[(size_t)grow*16 + uu] = v;
        }
    }
}

// ---------------------------------------------------------------------------
// csr_edge: one block per B-bucket (64 keys): regroup adj1 + a1h (mean px)
// + global a1h max (one atomicMax per block, 157 total).
__global__ __launch_bounds__(256) void csr_edge(
        const uint* __restrict__ bktB, const int* __restrict__ gcurB,
        int* __restrict__ adj1, int2* __restrict__ rg1,
        const float* __restrict__ px, float* __restrict__ a1h,
        uint* __restrict__ g1key, int M)
{
    __shared__ int h[64], sc[64], cu[64];
    __shared__ float fsum[64];
    int t = threadIdx.x;
    int b = blockIdx.x;
    int sb = b*CAPB;
    int total = gcurB[b] - sb;
    int kb = b << 6;
    if (t < 64){ h[t] = 0; fsum[t] = 0.f; }
    __syncthreads();
    const uint* src = bktB + sb;
    for (int i = t; i < total; i += 256)
        atomicAdd(&h[(int)(src[i] >> 16) - kb], 1);
    __syncthreads();
    if (t < 64) sc[t] = h[t];
    __syncthreads();
    for (int off = 1; off < 64; off <<= 1){
        int v = (t < 64 && t >= off) ? sc[t - off] : 0;
        __syncthreads();
        if (t < 64) sc[t] += v;
        __syncthreads();
    }
    if (t < 64){ sc[t] -= h[t]; cu[t] = sc[t]; }
    __syncthreads();
    for (int i = t; i < total; i += 256){
        uint v = src[i];
        int k = (int)(v >> 16) - kb;
        int pos = atomicAdd(&cu[k], 1);
        int n = (int)(v & 0xFFFFu);
        adj1[sb + pos] = n;
        atomicAdd(&fsum[k], px[n]);
    }
    __syncthreads();
    if (t < 64){
        int key = kb + t;
        float av = -3.4e38f;
        if (key < M){
            av = (h[t] > 0) ? fsum[t]/(float)h[t] : 0.f;
            rg1[key] = make_int2(sb + sc[t], sb + sc[t] + h[t]);
            a1h[key] = av;
        }
        #pragma unroll
        for (int off = 32; off > 0; off >>= 1)
            av = fmaxf(av, __shfl_xor(av, off));
        if (t == 0) atomicMax(g1key, fenc(av));
    }
}

// csr_node: one block per A-bucket (256 keys): regroup adj0 through LDS
// + round-1 stats (single pass, global-bound shift) + Dinv
// + G2 bound: a2h[m] <= max(0, max pxl) (one atomicMax per block, 196 total).
__global__ __launch_bounds__(256) void csr_node(
        const uint* __restrict__ bktA, const int* __restrict__ gcurA,
        int* __restrict__ adj0, int2* __restrict__ rg0,
        const float* __restrict__ a1x, const float* __restrict__ a1h,
        const float* __restrict__ hw, const float* __restrict__ pxl,
        const uint* __restrict__ g1key, uint* __restrict__ g2key,
        float4* __restrict__ pk1, float* __restrict__ Dinv, int N)
{
    __shared__ int h[256], sc[256], cu[256];
    __shared__ uint sm[CAPA];           // 32 KB
    __shared__ float wmax[4];
    int t = threadIdx.x;
    int b = blockIdx.x;
    int sb = b*CAPA;
    int total = gcurA[b] - sb;
    int kb = b << 8;
    float G1 = fdec(*g1key);
    h[t] = 0;
    __syncthreads();
    const uint* src = bktA + sb;
    for (int i = t; i < total; i += 256)
        atomicAdd(&h[(int)(src[i] >> 14) - kb], 1);
    __syncthreads();
    sc[t] = h[t];
    __syncthreads();
    for (int off = 1; off < 256; off <<= 1){
        int v = (t >= off) ? sc[t - off] : 0;
        __syncthreads();
        sc[t] += v;
        __syncthreads();
    }
    sc[t] -= h[t];
    cu[t] = sc[t];
    __syncthreads();
    for (int i = t; i < total; i += 256){
        uint v = src[i];
        int k = (int)(v >> 14) - kb;
        int pos = atomicAdd(&cu[k], 1);
        sm[pos] = v & 0x3FFFu;
    }
    __syncthreads();
    for (int i = t; i < total; i += 256) adj0[sb + i] = (int)sm[i];
    int key = kb + t;
    float pl = (key < N) ? pxl[key] : 0.f;
    if (key < N){
        int deg = h[t], beg = sc[t];
        rg0[key] = make_int2(sb + beg, sb + beg + deg);
        float ax = a1x[key];
        float mx = leaky(ax + G1);      // upper bound of all logits (monotonic)
        float se = 0.f, wsum = 0.f;
        for (int j = 0; j < deg; j++){
            int m = (int)sm[beg + j];
            wsum += hw[m];
            se += expf(leaky(ax + a1h[m]) - mx);
        }
        pk1[key] = make_float4(ax, mx, (deg > 0) ? 1.f/se : 0.f, pl);
        Dinv[key] = (wsum > 0.f) ? 1.f/wsum : 0.f;
    }
    // block max of pxl -> G2 bound (a2h is an alpha-weighted mean of pxl)
    float pv = pl;
    #pragma unroll
    for (int off = 32; off > 0; off >>= 1) pv = fmaxf(pv, __shfl_xor(pv, off));
    if ((t & 63) == 0) wmax[t >> 6] = pv;
    __syncthreads();
    if (t == 0){
        float bm = fmaxf(fmaxf(wmax[0], wmax[1]), fmaxf(wmax[2], wmax[3]));
        atomicMax(g2key, fenc(fmaxf(bm, 0.f)));
    }
}

// ---------------------------------------------------------------------------
// out_e (bf16): one wave per hyperedge; 8 edge-rows in flight. NO atomics.
__global__ __launch_bounds__(256) void agg_oute(
    const int2* __restrict__ rg1, const int* __restrict__ adj1,
    const float4* __restrict__ pk1, const float* __restrict__ a1h,
    const uint* __restrict__ xlb, uint* __restrict__ outeb,
    float* __restrict__ a2h, int M)
{
    int m = blockIdx.x*4 + (threadIdx.x >> 6);
    int lane = threadIdx.x & 63;
    if (m >= M) return;
    int2 r = rg1[m];
    int b = r.x, e = r.y, deg = e - b;
    float binv = deg > 0 ? 1.f/(float)deg : 0.f;
    float ah = a1h[m];
    int sub = lane >> 4, cg = lane & 15;
    const uint4* x4p = (const uint4*)xlb;
    float acc[8] = {0,0,0,0,0,0,0,0};
    float sca = 0.f;
    for (int base = b; base < e; base += 64){
        int cnt = min(64, e - base);
        int n = 0; float al = 0.f;
        if (lane < cnt){
            n = adj1[base + lane];
            float4 g = pk1[n];                 // (a1x, mx1, is1, pxl)
            al = expf(leaky(g.x + ah) - g.y) * g.z;
            sca += al * g.w;
        }
        int t4 = 0;
        for (; t4 + 8 <= cnt; t4 += 8){
            int   nb0 = __shfl(n,  t4 + sub);
            float ab0 = __shfl(al, t4 + sub);
            int   nb1 = __shfl(n,  t4 + 4 + sub);
            float ab1 = __shfl(al, t4 + 4 + sub);
            uint4 v0 = x4p[(size_t)nb0*16 + cg];
            uint4 v1 = x4p[(size_t)nb1*16 + cg];
            acc[0] += ab0*blo(v0.x); acc[1] += ab0*bhi(v0.x);
            acc[2] += ab0*blo(v0.y); acc[3] += ab0*bhi(v0.y);
            acc[4] += ab0*blo(v0.z); acc[5] += ab0*bhi(v0.z);
            acc[6] += ab0*blo(v0.w); acc[7] += ab0*bhi(v0.w);
            acc[0] += ab1*blo(v1.x); acc[1] += ab1*bhi(v1.x);
            acc[2] += ab1*blo(v1.y); acc[3] += ab1*bhi(v1.y);
            acc[4] += ab1*blo(v1.z); acc[5] += ab1*bhi(v1.z);
            acc[6] += ab1*blo(v1.w); acc[7] += ab1*bhi(v1.w);
        }
        for (; t4 < cnt; t4 += 4){
            int   nb = __shfl(n,  t4 + sub);   // al=0 for tail lanes -> no-op
            float ab = __shfl(al, t4 + sub);
            uint4 v = x4p[(size_t)nb*16 + cg];
            acc[0] += ab*blo(v.x); acc[1] += ab*bhi(v.x);
            acc[2] += ab*blo(v.y); acc[3] += ab*bhi(v.y);
            acc[4] += ab*blo(v.z); acc[5] += ab*bhi(v.z);
            acc[6] += ab*blo(v.w); acc[7] += ab*bhi(v.w);
        }
    }
    #pragma unroll
    for (int i = 0; i < 8; i++){
        acc[i] += __shfl_xor(acc[i], 32);
        acc[i] += __shfl_xor(acc[i], 16);
    }
    #pragma unroll
    for (int off = 32; off > 0; off >>= 1) sca += __shfl_xor(sca, off);
    if (lane < 16){
        uint4 w;
        w.x = bf2(binv*acc[0], binv*acc[1]);
        w.y = bf2(binv*acc[2], binv*acc[3]);
        w.z = bf2(binv*acc[4], binv*acc[5]);
        w.w = bf2(binv*acc[6], binv*acc[7]);
        ((uint4*)outeb)[(size_t)m*16 + cg] = w;
    }
    if (lane == 0) a2h[m] = binv*sca;
}

// out[n] = Dinv/se * sum exp(..) * out_e[m] : one wave per node; stats fused,
// global-bound shift (no max pass).
__global__ __launch_bounds__(256) void agg_outn(
    const int2* __restrict__ rg0, const int* __restrict__ adj0,
    const float* __restrict__ a2x, const float* __restrict__ a2h,
    const float* __restrict__ Dinv, const uint* __restrict__ outeb,
    const uint* __restrict__ g2key, float* __restrict__ out, int N)
{
    int n = blockIdx.x*4 + (threadIdx.x >> 6);
    int lane = threadIdx.x & 63;
    if (n >= N) return;
    int2 r = rg0[n];
    int b = r.x, e = r.y;
    float ax = a2x[n];
    float mx = leaky(ax + fdec(*g2key));   // upper bound (leaky monotonic)
    int sub = lane >> 4, cg = lane & 15;
    const uint4* o4p = (const uint4*)outeb;
    float acc[8] = {0,0,0,0,0,0,0,0};
    float sa = 0.f;
    for (int base = b; base < e; base += 64){
        int cnt = min(64, e - base);
        int m = 0; float al = 0.f;
        if (lane < cnt){
            m = adj0[base + lane];
            al = expf(leaky(ax + a2h[m]) - mx);
            sa += al;
        }
        int t4 = 0;
        for (; t4 + 8 <= cnt; t4 += 8){
            int   mb0 = __shfl(m,  t4 + sub);
            float ab0 = __shfl(al, t4 + sub);
            int   mb1 = __shfl(m,  t4 + 4 + sub);
            float ab1 = __shfl(al, t4 + 4 + sub);
            uint4 v0 = o4p[(size_t)mb0*16 + cg];
            uint4 v1 = o4p[(size_t)mb1*16 + cg];
            acc[0] += ab0*blo(v0.x); acc[1] += ab0*bhi(v0.x);
            acc[2] += ab0*blo(v0.y); acc[3] += ab0*bhi(v0.y);
            acc[4] += ab0*blo(v0.z); acc[5] += ab0*bhi(v0.z);
            acc[6] += ab0*blo(v0.w); acc[7] += ab0*bhi(v0.w);
            acc[0] += ab1*blo(v1.x); acc[1] += ab1*bhi(v1.x);
            acc[2] += ab1*blo(v1.y); acc[3] += ab1*bhi(v1.y);
            acc[4] += ab1*blo(v1.z); acc[5] += ab1*bhi(v1.z);
            acc[6] += ab1*blo(v1.w); acc[7] += ab1*bhi(v1.w);
        }
        for (; t4 < cnt; t4 += 4){
            int   mb = __shfl(m,  t4 + sub);
            float ab = __shfl(al, t4 + sub);
            uint4 v = o4p[(size_t)mb*16 + cg];
            acc[0] += ab*blo(v.x); acc[1] += ab*bhi(v.x);
            acc[2] += ab*blo(v.y); acc[3] += ab*bhi(v.y);
            acc[4] += ab*blo(v.z); acc[5] += ab*bhi(v.z);
            acc[6] += ab*blo(v.w); acc[7] += ab*bhi(v.w);
        }
    }
    #pragma unroll
    for (int off = 32; off > 0; off >>= 1) sa += __shfl_xor(sa, off);
    #pragma unroll
    for (int i = 0; i < 8; i++){
        acc[i] += __shfl_xor(acc[i], 32);
        acc[i] += __shfl_xor(acc[i], 16);
    }
    float scale = (sa > 0.f) ? Dinv[n]/sa : 0.f;
    if (lane < 16){
        float4 o0 = make_float4(scale*acc[0], scale*acc[1], scale*acc[2], scale*acc[3]);
        float4 o1 = make_float4(scale*acc[4], scale*acc[5], scale*acc[6], scale*acc[7]);
        ((float4*)out)[(size_t)n*32 + cg*2]     = o0;
        ((float4*)out)[(size_t)n*32 + cg*2 + 1] = o1;
    }
}

// ---------------------------------------------------------------------------
extern "C" void kernel_launch(void* const* d_in, const int* in_sizes, int n_in,
                              void* d_out, int out_size, void* d_ws, size_t ws_size,
                              hipStream_t stream){
    const float* x    = (const float*)d_in[0];
    const void*  hidx = d_in[1];
    const float* hw   = (const float*)d_in[2];
    const float* W1   = (const float*)d_in[3];
    const float* W2   = (const float*)d_in[4];
    const float* W3   = (const float*)d_in[5];
    const float* att  = (const float*)d_in[6];
    const float* att2 = (const float*)d_in[7];
    float* out = (float*)d_out;

    const int N = in_sizes[0] / DF;
    const int E = in_sizes[1] / 2;
    const int M = in_sizes[2];

    char* ws = (char*)d_ws;
    size_t o = 0;
    auto take = [&](size_t bytes) -> char* {
        char* p = ws + o;
        o += (bytes + 255) & ~(size_t)255;
        return p;
    };
    const int nbA = (N + 255) >> 8;     // node-side buckets
    const int nbB = (M + 63) >> 6;      // hyperedge-side buckets

    uint*   xlb  = (uint*)  take((size_t)N*64*4);
    uint*   outeb= (uint*)  take((size_t)M*64*4);
    float*  a1x  = (float*) take((size_t)N*4);
    float*  a2x  = (float*) take((size_t)N*4);
    float*  px   = (float*) take((size_t)N*4);
    float*  pxl  = (float*) take((size_t)N*4);
    float*  Dinv = (float*) take((size_t)N*4);
    float*  a1h  = (float*) take((size_t)M*4);
    float*  a2h  = (float*) take((size_t)M*4);
    float4* pk1  = (float4*)take((size_t)N*16);
    float*  w2a  = (float*) take(DF*4);
    float*  v1   = (float*) take(DF*4);
    float*  v2   = (float*) take(DF*4);
    float*  v3   = (float*) take(DF*4);
    uint*   W1t  = (uint*)  take(128*64*4);
    int2*   rg0  = (int2*)  take((size_t)N*8);
    int2*   rg1  = (int2*)  take((size_t)M*8);
    int*    gcurA= (int*)   take(256*4);
    int*    gcurB= (int*)   take(256*4);
    uint*   bktA = (uint*)  take((size_t)nbA*CAPA*4 + TILE*4);
    uint*   bktB = (uint*)  take((size_t)nbB*CAPB*4 + TILE*4);
    int*    adj0 = (int*)   take((size_t)nbA*CAPA*4);
    int*    adj1 = (int*)   take((size_t)nbB*CAPB*4);
    int*    ctrl = (int*)   take(256);   // [0]=flag [1]=g1key [2]=g2key

    const int SC = (E + TILE - 1)/TILE;
    const int GB = (N + 127)/128;

    // 1. flag + cursors + ctrl init + matvecs + W1t
    prep<<<11, 256, 0, stream>>>((const uint*)hidx, ctrl, gcurA, gcurB,
                                 W1, W2, W3, att, att2, w2a, v1, v2, v3, W1t, E);
    // 2. multisplit | MFMA gemm (fused, independent block ranges)
    scatter_gemm<<<SC + GB, 512, 0, stream>>>(hidx, ctrl, gcurA, gcurB,
                                 bktA, bktB, x, W1t, w2a, v1, v2, v3,
                                 xlb, a1x, a2x, px, pxl, E, N, SC);
    // 3. hyperedge-side CSR + a1h + G1
    csr_edge<<<nbB, 256, 0, stream>>>(bktB, gcurB, adj1, rg1, px, a1h,
                                      (uint*)&ctrl[1], M);
    // 4. node-side CSR + round-1 stats + Dinv + G2 bound
    csr_node<<<nbA, 256, 0, stream>>>(bktA, gcurA, adj0, rg0,
                                      a1x, a1h, hw, pxl, (uint*)&ctrl[1],
                                      (uint*)&ctrl[2], pk1, Dinv, N);
    // 5. round-1 aggregation (no atomics)
    agg_oute<<<(M + 3)/4, 256, 0, stream>>>(rg1, adj1, pk1, a1h, xlb, outeb,
                                            a2h, M);
    // 6. round 2 (stats fused, bound shift)
    agg_outn<<<(N + 3)/4, 256, 0, stream>>>(rg0, adj0, a2x, a2h, Dinv, outeb,
                                            (uint*)&ctrl[2], out, N);
}

// Round 14
// 123.328 us; speedup vs baseline: 1.4336x; 1.0396x over previous
//
#include <hip/hip_runtime.h>
#include <math.h>

#define DF 128      // feature dim
#define TILE 8192   // edges per scatter block
#define CAPA 8192   // bucket capacity, node side (mean 4081)
#define CAPB 10240  // bucket capacity, hyperedge side (mean 5096)
typedef unsigned int uint;
typedef __attribute__((ext_vector_type(8))) short bf16x8;
typedef __attribute__((ext_vector_type(4))) float f32x4;

__device__ __forceinline__ float leaky(float s){ return s > 0.f ? s : 0.2f*s; }

// f32 -> bf16 round-to-nearest-even, packed pair
__device__ __forceinline__ uint bfr(float f){
    uint u = __float_as_uint(f);
    return (u + 0x7fffu + ((u >> 16) & 1u)) >> 16;
}
__device__ __forceinline__ uint bf2(float a, float b){ return bfr(a) | (bfr(b) << 16); }
__device__ __forceinline__ float blo(uint v){ return __uint_as_float(v << 16); }
__device__ __forceinline__ float bhi(uint v){ return __uint_as_float(v & 0xffff0000u); }

// orderable-uint encoding for float atomicMax
__device__ __forceinline__ uint fenc(float f){
    uint u = __float_as_uint(f);
    return (u & 0x80000000u) ? ~u : (u | 0x80000000u);
}
__device__ __forceinline__ float fdec(uint k){
    return (k & 0x80000000u) ? __uint_as_float(k ^ 0x80000000u) : __uint_as_float(~k);
}

__device__ __forceinline__ void load_edge(const void* raw, int is64, int E, int e,
                                          int& n, int& m){
    if (is64){
        const long long* p = (const long long*)raw;
        n = (int)p[e]; m = (int)p[(long long)E + e];
    } else {
        const int* p = (const int*)raw;
        n = p[e]; m = p[E + e];
    }
}

// ---------------------------------------------------------------------------
// prep: b0 = int64 flag + bucket cursors + ctrl init ; b1,b2 = matvecs ;
// b3..b10 = W1t bf16 transpose.
__global__ __launch_bounds__(256) void prep(
        const uint* __restrict__ raw, int* __restrict__ ctrl,
        int* __restrict__ gcurA, int* __restrict__ gcurB,
        const float* __restrict__ W1, const float* __restrict__ W2,
        const float* __restrict__ W3,
        const float* __restrict__ att, const float* __restrict__ att2,
        float* __restrict__ w2a, float* __restrict__ v1,
        float* __restrict__ v2, float* __restrict__ v3,
        uint* __restrict__ W1t, int E)
{
    int t = threadIdx.x;
    int bid = blockIdx.x;
    if (bid == 0){
        __shared__ int cnt;
        gcurA[t] = t*CAPA;
        gcurB[t] = t*CAPB;
        if (t == 0){ cnt = 0; ctrl[1] = 0; ctrl[2] = 0; }   // g1key, g2key
        __syncthreads();
        int nz = 0;
        for (int i = 0; i < 4; i++){
            int w = 2*(t*4 + i) + 1;    // odd (high) words, int64 => all zero
            if (w < 2*E) nz += (raw[w] != 0u);
        }
        atomicAdd(&cnt, nz);
        __syncthreads();
        if (t == 0) ctrl[0] = (cnt == 0) ? 1 : 0;
    } else if (bid == 1){
        int d = t & 127;
        const float* W = (t < 128) ? W2 : W1;
        const float* a = (t < 128) ? (att + 128) : att;
        float s = 0.f;
        for (int f = 0; f < 128; f++) s += W[d*128 + f]*a[f];
        if (t < 128) w2a[d] = s; else v1[d] = s;
    } else if (bid == 2){
        __shared__ float sw3a[128];
        int d = t & 127;
        const float* W = (t < 128) ? W1 : W3;
        const float* a = (t < 128) ? att2 : (att2 + 128);
        float s = 0.f;
        for (int f = 0; f < 128; f++) s += W[d*128 + f]*a[f];
        if (t < 128) v2[d] = s; else sw3a[d] = s;
        __syncthreads();
        if (t < 128){
            float s2 = 0.f;
            for (int f = 0; f < 128; f++) s2 += W1[t*128 + f]*sw3a[f];
            v3[t] = s2;
        }
    } else {
        int base = (bid - 3)*1024;
        for (int p = base + t; p < base + 1024; p += 256){
            int f = p >> 6, dh = p & 63;
            W1t[p] = bf2(W1[(2*dh)*128 + f], W1[(2*dh + 1)*128 + f]);
        }
    }
}

// ---------------------------------------------------------------------------
// FUSED: blocks [0,SC) = multisplit scatter ; blocks [SC,SC+GB) = MFMA gemm.
// 512 threads, 72KB LDS union.
__global__ __launch_bounds__(512) void scatter_gemm(
        const void* __restrict__ raw, const int* __restrict__ ctrl,
        int* __restrict__ gcurA, int* __restrict__ gcurB,
        uint* __restrict__ bktA, uint* __restrict__ bktB,
        const float* __restrict__ X, const uint* __restrict__ W1t,
        const float* __restrict__ w2a, const float* __restrict__ v1,
        const float* __restrict__ v2, const float* __restrict__ v3,
        uint* __restrict__ xlb, float* __restrict__ a1x, float* __restrict__ a2x,
        float* __restrict__ px, float* __restrict__ pxl,
        int E, int N, int SC)
{
    __shared__ char smem[73728];        // 72 KB
    int t = threadIdx.x;
    int bid = blockIdx.x;

    if (bid < SC){
        // ---------------- multisplit scatter ----------------
        uint* stA = (uint*)smem;                 // 32 KB
        uint* stB = (uint*)(smem + 32768);       // 32 KB
        int*  hA  = (int*)(smem + 65536);
        int*  scA = hA + 256; int* cuA = hA + 512; int* bA = hA + 768;
        int*  hB  = hA + 1024; int* scB = hA + 1280; int* cuB = hA + 1536; int* bB = hA + 1792;
        if (t < 256){ hA[t] = 0; hB[t] = 0; }
        __syncthreads();
        int tb = bid*TILE;
        int cnt = min(TILE, E - tb);
        int is64 = ctrl[0];
        for (int i = t; i < cnt; i += 512){
            int n, m; load_edge(raw, is64, E, tb + i, n, m);
            atomicAdd(&hA[n >> 8], 1);
            atomicAdd(&hB[m >> 6], 1);
        }
        __syncthreads();
        if (t < 256){ scA[t] = hA[t]; scB[t] = hB[t]; }
        __syncthreads();
        for (int off = 1; off < 256; off <<= 1){
            int vA = 0, vB = 0;
            if (t < 256 && t >= off){ vA = scA[t - off]; vB = scB[t - off]; }
            __syncthreads();
            if (t < 256){ scA[t] += vA; scB[t] += vB; }
            __syncthreads();
        }
        if (t < 256){
            scA[t] -= hA[t]; scB[t] -= hB[t];
            cuA[t] = scA[t]; cuB[t] = scB[t];
            bA[t] = atomicAdd(&gcurA[t], hA[t]);
            bB[t] = atomicAdd(&gcurB[t], hB[t]);
        }
        __syncthreads();
        for (int i = t; i < cnt; i += 512){
            int n, m; load_edge(raw, is64, E, tb + i, n, m);
            int pA = atomicAdd(&cuA[n >> 8], 1);
            stA[pA] = ((uint)n << 14) | (uint)m;
            int pB = atomicAdd(&cuB[m >> 6], 1);
            stB[pB] = ((uint)m << 16) | (uint)n;
        }
        __syncthreads();
        for (int p = t; p < cnt; p += 512){
            uint v = stA[p]; int b = (int)(v >> 22);
            bktA[bA[b] + (p - scA[b])] = v;
            uint w = stB[p]; int c = (int)(w >> 22);
            bktB[bB[c] + (p - scB[c])] = w;
        }
    } else {
        // ---------------- gemm: 128 rows, 8 waves ----------------
        char* lds = smem;                        // A: 32 KB ; Bt at +32768: 32 KB
        int lane = t & 63, wv = t >> 6;
        int row0 = (bid - SC)*128;
        {   // stage Bt swizzled
            const uint4* g = (const uint4*)W1t;
            #pragma unroll
            for (int i = 0; i < 4; i++){
                int u = i*512 + t;
                int col = u >> 4;
                uint4 v = g[u];
                *(uint4*)(lds + 32768 + ((u*16) ^ ((col & 7) << 4))) = v;
            }
        }
        {   // stage A (f32->bf16) + exact f32 row dots
            int cg = t & 31;
            float4 c_px = ((const float4*)w2a)[cg];
            float4 c_a1 = ((const float4*)v1 )[cg];
            float4 c_a2 = ((const float4*)v2 )[cg];
            float4 c_pl = ((const float4*)v3 )[cg];
            #pragma unroll
            for (int i = 0; i < 8; i++){
                int idx = i*512 + t;
                int rl = idx >> 5;
                int row = row0 + rl;
                float4 xv = make_float4(0.f, 0.f, 0.f, 0.f);
                if (row < N) xv = ((const float4*)X)[(size_t)row*32 + cg];
                uint2 pk; pk.x = bf2(xv.x, xv.y); pk.y = bf2(xv.z, xv.w);
                *(uint2*)(lds + rl*256 + ((cg*8) ^ ((rl & 7) << 4))) = pk;
                float d0 = xv.x*c_px.x + xv.y*c_px.y + xv.z*c_px.z + xv.w*c_px.w;
                float d1 = xv.x*c_a1.x + xv.y*c_a1.y + xv.z*c_a1.z + xv.w*c_a1.w;
                float d2 = xv.x*c_a2.x + xv.y*c_a2.y + xv.z*c_a2.z + xv.w*c_a2.w;
                float d3 = xv.x*c_pl.x + xv.y*c_pl.y + xv.z*c_pl.z + xv.w*c_pl.w;
                #pragma unroll
                for (int off = 16; off > 0; off >>= 1){
                    d0 += __shfl_xor(d0, off); d1 += __shfl_xor(d1, off);
                    d2 += __shfl_xor(d2, off); d3 += __shfl_xor(d3, off);
                }
                if (cg == 0 && row < N){
                    px[row] = d0; a1x[row] = d1; a2x[row] = d2; pxl[row] = d3;
                }
            }
        }
        __syncthreads();
        f32x4 acc[8];
        #pragma unroll
        for (int i = 0; i < 8; i++) acc[i] = (f32x4){0.f, 0.f, 0.f, 0.f};
        int arow = wv*16 + (lane & 15);
        int aswz = (arow & 7) << 4;
        int bswz = (lane & 7) << 4;
        #pragma unroll
        for (int ks = 0; ks < 4; ks++){
            int au16 = ((lane >> 4) + ks*4)*16;
            bf16x8 af = *(const bf16x8*)(lds + arow*256 + (au16 ^ aswz));
            #pragma unroll
            for (int nf = 0; nf < 8; nf++){
                int bcol = nf*16 + (lane & 15);
                bf16x8 bf = *(const bf16x8*)(lds + 32768 + bcol*256 + (au16 ^ bswz));
                acc[nf] = __builtin_amdgcn_mfma_f32_16x16x32_bf16(af, bf, acc[nf], 0, 0, 0);
            }
        }
        __syncthreads();
        #pragma unroll
        for (int nf = 0; nf < 8; nf++){
            #pragma unroll
            for (int reg = 0; reg < 4; reg++){
                int rl = wv*16 + (lane >> 4)*4 + reg;
                int col = nf*16 + (lane & 15);
                *(unsigned short*)(lds + rl*256 + ((col*2) ^ ((rl & 7) << 4))) =
                    (unsigned short)bfr(acc[nf][reg]);
            }
        }
        __syncthreads();
        #pragma unroll
        for (int j = 0; j < 4; j++){
            int unit = j*64 + lane;
            int rl = wv*16 + (unit >> 4);
            int uu = unit & 15;
            uint4 v = *(const uint4*)(lds + rl*256 + ((uu*16) ^ ((rl & 7) << 4)));
            int grow = row0 + rl;
            if (grow < N) ((uint4*)xlb)[(size_t)grow*16 + uu] = v;
        }
    }
}

// ---------------------------------------------------------------------------
// csr_edge: one block per B-bucket (64 keys): regroup adj1 + a1h (mean px)
// + global a1h max (one atomicMax per block, 157 total).
__global__ __launch_bounds__(256) void csr_edge(
        const uint* __restrict__ bktB, const int* __restrict__ gcurB,
        int* __restrict__ adj1, int2* __restrict__ rg1,
        const float* __restrict__ px, float* __restrict__ a1h,
        uint* __restrict__ g1key, int M)
{
    __shared__ int h[64], sc[64], cu[64];
    __shared__ float fsum[64];
    int t = threadIdx.x;
    int b = blockIdx.x;
    int sb = b*CAPB;
    int total = gcurB[b] - sb;
    int kb = b << 6;
    if (t < 64){ h[t] = 0; fsum[t] = 0.f; }
    __syncthreads();
    const uint* src = bktB + sb;
    for (int i = t; i < total; i += 256)
        atomicAdd(&h[(int)(src[i] >> 16) - kb], 1);
    __syncthreads();
    if (t < 64) sc[t] = h[t];
    __syncthreads();
    for (int off = 1; off < 64; off <<= 1){
        int v = (t < 64 && t >= off) ? sc[t - off] : 0;
        __syncthreads();
        if (t < 64) sc[t] += v;
        __syncthreads();
    }
    if (t < 64){ sc[t] -= h[t]; cu[t] = sc[t]; }
    __syncthreads();
    for (int i = t; i < total; i += 256){
        uint v = src[i];
        int k = (int)(v >> 16) - kb;
        int pos = atomicAdd(&cu[k], 1);
        int n = (int)(v & 0xFFFFu);
        adj1[sb + pos] = n;
        atomicAdd(&fsum[k], px[n]);
    }
    __syncthreads();
    if (t < 64){
        int key = kb + t;
        float av = -3.4e38f;
        if (key < M){
            av = (h[t] > 0) ? fsum[t]/(float)h[t] : 0.f;
            rg1[key] = make_int2(sb + sc[t], sb + sc[t] + h[t]);
            a1h[key] = av;
        }
        #pragma unroll
        for (int off = 32; off > 0; off >>= 1)
            av = fmaxf(av, __shfl_xor(av, off));
        if (t == 0) atomicMax(g1key, fenc(av));
    }
}

// csr_node: one block per A-bucket (256 keys): regroup adj0 through LDS
// + round-1 stats (single pass, global-bound shift) + Dinv
// + G2 bound: a2h[m] <= max(0, max pxl) (one atomicMax per block, 196 total).
__global__ __launch_bounds__(256) void csr_node(
        const uint* __restrict__ bktA, const int* __restrict__ gcurA,
        int* __restrict__ adj0, int2* __restrict__ rg0,
        const float* __restrict__ a1x, const float* __restrict__ a1h,
        const float* __restrict__ hw, const float* __restrict__ pxl,
        const uint* __restrict__ g1key, uint* __restrict__ g2key,
        float4* __restrict__ pk1, float* __restrict__ Dinv, int N)
{
    __shared__ int h[256], sc[256], cu[256];
    __shared__ uint sm[CAPA];           // 32 KB
    __shared__ float wmax[4];
    int t = threadIdx.x;
    int b = blockIdx.x;
    int sb = b*CAPA;
    int total = gcurA[b] - sb;
    int kb = b << 8;
    float G1 = fdec(*g1key);
    h[t] = 0;
    __syncthreads();
    const uint* src = bktA + sb;
    for (int i = t; i < total; i += 256)
        atomicAdd(&h[(int)(src[i] >> 14) - kb], 1);
    __syncthreads();
    sc[t] = h[t];
    __syncthreads();
    for (int off = 1; off < 256; off <<= 1){
        int v = (t >= off) ? sc[t - off] : 0;
        __syncthreads();
        sc[t] += v;
        __syncthreads();
    }
    sc[t] -= h[t];
    cu[t] = sc[t];
    __syncthreads();
    for (int i = t; i < total; i += 256){
        uint v = src[i];
        int k = (int)(v >> 14) - kb;
        int pos = atomicAdd(&cu[k], 1);
        sm[pos] = v & 0x3FFFu;
    }
    __syncthreads();
    for (int i = t; i < total; i += 256) adj0[sb + i] = (int)sm[i];
    int key = kb + t;
    float pl = (key < N) ? pxl[key] : 0.f;
    if (key < N){
        int deg = h[t], beg = sc[t];
        rg0[key] = make_int2(sb + beg, sb + beg + deg);
        float ax = a1x[key];
        float mx = leaky(ax + G1);      // upper bound of all logits (monotonic)
        float se = 0.f, wsum = 0.f;
        for (int j = 0; j < deg; j++){
            int m = (int)sm[beg + j];
            wsum += hw[m];
            se += expf(leaky(ax + a1h[m]) - mx);
        }
        pk1[key] = make_float4(ax, mx, (deg > 0) ? 1.f/se : 0.f, pl);
        Dinv[key] = (wsum > 0.f) ? 1.f/wsum : 0.f;
    }
    // block max of pxl -> G2 bound (a2h is an alpha-weighted mean of pxl)
    float pv = pl;
    #pragma unroll
    for (int off = 32; off > 0; off >>= 1) pv = fmaxf(pv, __shfl_xor(pv, off));
    if ((t & 63) == 0) wmax[t >> 6] = pv;
    __syncthreads();
    if (t == 0){
        float bm = fmaxf(fmaxf(wmax[0], wmax[1]), fmaxf(wmax[2], wmax[3]));
        atomicMax(g2key, fenc(fmaxf(bm, 0.f)));
    }
}

// ---------------------------------------------------------------------------
// out_e (bf16): TWO waves per hyperedge (halved edge ranges, LDS combine) for
// 2x memory-level parallelism; 8 edge-rows in flight per wave. NO atomics.
__global__ __launch_bounds__(256) void agg_oute(
    const int2* __restrict__ rg1, const int* __restrict__ adj1,
    const float4* __restrict__ pk1, const float* __restrict__ a1h,
    const uint* __restrict__ xlb, uint* __restrict__ outeb,
    float* __restrict__ a2h, int M)
{
    __shared__ float part[2][132];      // [slot][128 acc | 128=sca]
    int t = threadIdx.x;
    int wv = t >> 6, lane = t & 63;
    int slot = wv >> 1, half = wv & 1;
    int m = blockIdx.x*2 + slot;
    int sub = lane >> 4, cg = lane & 15;
    const uint4* x4p = (const uint4*)xlb;
    float acc[8] = {0,0,0,0,0,0,0,0};
    float sca = 0.f;
    float binv = 0.f;
    if (m < M){
        int2 r = rg1[m];
        int b = r.x, e = r.y, deg = e - b;
        binv = deg > 0 ? 1.f/(float)deg : 0.f;
        float ah = a1h[m];
        int hl = (deg + 1) >> 1;
        int hb = b + half*hl;
        int he = min(e, hb + hl);
        for (int base = hb; base < he; base += 64){
            int cnt = min(64, he - base);
            int n = 0; float al = 0.f;
            if (lane < cnt){
                n = adj1[base + lane];
                float4 g = pk1[n];                 // (a1x, mx1, is1, pxl)
                al = expf(leaky(g.x + ah) - g.y) * g.z;
                sca += al * g.w;
            }
            int t4 = 0;
            for (; t4 + 8 <= cnt; t4 += 8){
                int   nb0 = __shfl(n,  t4 + sub);
                float ab0 = __shfl(al, t4 + sub);
                int   nb1 = __shfl(n,  t4 + 4 + sub);
                float ab1 = __shfl(al, t4 + 4 + sub);
                uint4 v0 = x4p[(size_t)nb0*16 + cg];
                uint4 v1 = x4p[(size_t)nb1*16 + cg];
                acc[0] += ab0*blo(v0.x); acc[1] += ab0*bhi(v0.x);
                acc[2] += ab0*blo(v0.y); acc[3] += ab0*bhi(v0.y);
                acc[4] += ab0*blo(v0.z); acc[5] += ab0*bhi(v0.z);
                acc[6] += ab0*blo(v0.w); acc[7] += ab0*bhi(v0.w);
                acc[0] += ab1*blo(v1.x); acc[1] += ab1*bhi(v1.x);
                acc[2] += ab1*blo(v1.y); acc[3] += ab1*bhi(v1.y);
                acc[4] += ab1*blo(v1.z); acc[5] += ab1*bhi(v1.z);
                acc[6] += ab1*blo(v1.w); acc[7] += ab1*bhi(v1.w);
            }
            for (; t4 < cnt; t4 += 4){
                int   nb = __shfl(n,  t4 + sub);   // al=0 tail lanes -> no-op
                float ab = __shfl(al, t4 + sub);
                uint4 v = x4p[(size_t)nb*16 + cg];
                acc[0] += ab*blo(v.x); acc[1] += ab*bhi(v.x);
                acc[2] += ab*blo(v.y); acc[3] += ab*bhi(v.y);
                acc[4] += ab*blo(v.z); acc[5] += ab*bhi(v.z);
                acc[6] += ab*blo(v.w); acc[7] += ab*bhi(v.w);
            }
        }
        #pragma unroll
        for (int i = 0; i < 8; i++){
            acc[i] += __shfl_xor(acc[i], 32);
            acc[i] += __shfl_xor(acc[i], 16);
        }
        #pragma unroll
        for (int off = 32; off > 0; off >>= 1) sca += __shfl_xor(sca, off);
    }
    // cross-wave combine: half 1 publishes, half 0 reduces + writes
    if (half == 1 && lane < 16){
        #pragma unroll
        for (int i = 0; i < 8; i++) part[slot][cg*8 + i] = acc[i];
        if (lane == 0) part[slot][128] = sca;
    }
    __syncthreads();
    if (half == 0 && m < M && lane < 16){
        uint4 w;
        w.x = bf2(binv*(acc[0] + part[slot][cg*8+0]), binv*(acc[1] + part[slot][cg*8+1]));
        w.y = bf2(binv*(acc[2] + part[slot][cg*8+2]), binv*(acc[3] + part[slot][cg*8+3]));
        w.z = bf2(binv*(acc[4] + part[slot][cg*8+4]), binv*(acc[5] + part[slot][cg*8+5]));
        w.w = bf2(binv*(acc[6] + part[slot][cg*8+6]), binv*(acc[7] + part[slot][cg*8+7]));
        ((uint4*)outeb)[(size_t)m*16 + cg] = w;
        if (lane == 0) a2h[m] = binv*(sca + part[slot][128]);
    }
}

// out[n] = Dinv/se * sum exp(..) * out_e[m] : one wave per node; stats fused,
// global-bound shift (no max pass).
__global__ __launch_bounds__(256) void agg_outn(
    const int2* __restrict__ rg0, const int* __restrict__ adj0,
    const float* __restrict__ a2x, const float* __restrict__ a2h,
    const float* __restrict__ Dinv, const uint* __restrict__ outeb,
    const uint* __restrict__ g2key, float* __restrict__ out, int N)
{
    int n = blockIdx.x*4 + (threadIdx.x >> 6);
    int lane = threadIdx.x & 63;
    if (n >= N) return;
    int2 r = rg0[n];
    int b = r.x, e = r.y;
    float ax = a2x[n];
    float mx = leaky(ax + fdec(*g2key));   // upper bound (leaky monotonic)
    int sub = lane >> 4, cg = lane & 15;
    const uint4* o4p = (const uint4*)outeb;
    float acc[8] = {0,0,0,0,0,0,0,0};
    float sa = 0.f;
    for (int base = b; base < e; base += 64){
        int cnt = min(64, e - base);
        int m = 0; float al = 0.f;
        if (lane < cnt){
            m = adj0[base + lane];
            al = expf(leaky(ax + a2h[m]) - mx);
            sa += al;
        }
        int t4 = 0;
        for (; t4 + 8 <= cnt; t4 += 8){
            int   mb0 = __shfl(m,  t4 + sub);
            float ab0 = __shfl(al, t4 + sub);
            int   mb1 = __shfl(m,  t4 + 4 + sub);
            float ab1 = __shfl(al, t4 + 4 + sub);
            uint4 v0 = o4p[(size_t)mb0*16 + cg];
            uint4 v1 = o4p[(size_t)mb1*16 + cg];
            acc[0] += ab0*blo(v0.x); acc[1] += ab0*bhi(v0.x);
            acc[2] += ab0*blo(v0.y); acc[3] += ab0*bhi(v0.y);
            acc[4] += ab0*blo(v0.z); acc[5] += ab0*bhi(v0.z);
            acc[6] += ab0*blo(v0.w); acc[7] += ab0*bhi(v0.w);
            acc[0] += ab1*blo(v1.x); acc[1] += ab1*bhi(v1.x);
            acc[2] += ab1*blo(v1.y); acc[3] += ab1*bhi(v1.y);
            acc[4] += ab1*blo(v1.z); acc[5] += ab1*bhi(v1.z);
            acc[6] += ab1*blo(v1.w); acc[7] += ab1*bhi(v1.w);
        }
        for (; t4 < cnt; t4 += 4){
            int   mb = __shfl(m,  t4 + sub);
            float ab = __shfl(al, t4 + sub);
            uint4 v = o4p[(size_t)mb*16 + cg];
            acc[0] += ab*blo(v.x); acc[1] += ab*bhi(v.x);
            acc[2] += ab*blo(v.y); acc[3] += ab*bhi(v.y);
            acc[4] += ab*blo(v.z); acc[5] += ab*bhi(v.z);
            acc[6] += ab*blo(v.w); acc[7] += ab*bhi(v.w);
        }
    }
    #pragma unroll
    for (int off = 32; off > 0; off >>= 1) sa += __shfl_xor(sa, off);
    #pragma unroll
    for (int i = 0; i < 8; i++){
        acc[i] += __shfl_xor(acc[i], 32);
        acc[i] += __shfl_xor(acc[i], 16);
    }
    float scale = (sa > 0.f) ? Dinv[n]/sa : 0.f;
    if (lane < 16){
        float4 o0 = make_float4(scale*acc[0], scale*acc[1], scale*acc[2], scale*acc[3]);
        float4 o1 = make_float4(scale*acc[4], scale*acc[5], scale*acc[6], scale*acc[7]);
        ((float4*)out)[(size_t)n*32 + cg*2]     = o0;
        ((float4*)out)[(size_t)n*32 + cg*2 + 1] = o1;
    }
}

// ---------------------------------------------------------------------------
extern "C" void kernel_launch(void* const* d_in, const int* in_sizes, int n_in,
                              void* d_out, int out_size, void* d_ws, size_t ws_size,
                              hipStream_t stream){
    const float* x    = (const float*)d_in[0];
    const void*  hidx = d_in[1];
    const float* hw   = (const float*)d_in[2];
    const float* W1   = (const float*)d_in[3];
    const float* W2   = (const float*)d_in[4];
    const float* W3   = (const float*)d_in[5];
    const float* att  = (const float*)d_in[6];
    const float* att2 = (const float*)d_in[7];
    float* out = (float*)d_out;

    const int N = in_sizes[0] / DF;
    const int E = in_sizes[1] / 2;
    const int M = in_sizes[2];

    char* ws = (char*)d_ws;
    size_t o = 0;
    auto take = [&](size_t bytes) -> char* {
        char* p = ws + o;
        o += (bytes + 255) & ~(size_t)255;
        return p;
    };
    const int nbA = (N + 255) >> 8;     // node-side buckets
    const int nbB = (M + 63) >> 6;      // hyperedge-side buckets

    uint*   xlb  = (uint*)  take((size_t)N*64*4);
    uint*   outeb= (uint*)  take((size_t)M*64*4);
    float*  a1x  = (float*) take((size_t)N*4);
    float*  a2x  = (float*) take((size_t)N*4);
    float*  px   = (float*) take((size_t)N*4);
    float*  pxl  = (float*) take((size_t)N*4);
    float*  Dinv = (float*) take((size_t)N*4);
    float*  a1h  = (float*) take((size_t)M*4);
    float*  a2h  = (float*) take((size_t)M*4);
    float4* pk1  = (float4*)take((size_t)N*16);
    float*  w2a  = (float*) take(DF*4);
    float*  v1   = (float*) take(DF*4);
    float*  v2   = (float*) take(DF*4);
    float*  v3   = (float*) take(DF*4);
    uint*   W1t  = (uint*)  take(128*64*4);
    int2*   rg0  = (int2*)  take((size_t)N*8);
    int2*   rg1  = (int2*)  take((size_t)M*8);
    int*    gcurA= (int*)   take(256*4);
    int*    gcurB= (int*)   take(256*4);
    uint*   bktA = (uint*)  take((size_t)nbA*CAPA*4 + TILE*4);
    uint*   bktB = (uint*)  take((size_t)nbB*CAPB*4 + TILE*4);
    int*    adj0 = (int*)   take((size_t)nbA*CAPA*4);
    int*    adj1 = (int*)   take((size_t)nbB*CAPB*4);
    int*    ctrl = (int*)   take(256);   // [0]=flag [1]=g1key [2]=g2key

    const int SC = (E + TILE - 1)/TILE;
    const int GB = (N + 127)/128;

    // 1. flag + cursors + ctrl init + matvecs + W1t
    prep<<<11, 256, 0, stream>>>((const uint*)hidx, ctrl, gcurA, gcurB,
                                 W1, W2, W3, att, att2, w2a, v1, v2, v3, W1t, E);
    // 2. multisplit | MFMA gemm (fused, independent block ranges)
    scatter_gemm<<<SC + GB, 512, 0, stream>>>(hidx, ctrl, gcurA, gcurB,
                                 bktA, bktB, x, W1t, w2a, v1, v2, v3,
                                 xlb, a1x, a2x, px, pxl, E, N, SC);
    // 3. hyperedge-side CSR + a1h + G1
    csr_edge<<<nbB, 256, 0, stream>>>(bktB, gcurB, adj1, rg1, px, a1h,
                                      (uint*)&ctrl[1], M);
    // 4. node-side CSR + round-1 stats + Dinv + G2 bound
    csr_node<<<nbA, 256, 0, stream>>>(bktA, gcurA, adj0, rg0,
                                      a1x, a1h, hw, pxl, (uint*)&ctrl[1],
                                      (uint*)&ctrl[2], pk1, Dinv, N);
    // 5. round-1 aggregation (2 waves/hyperedge, no atomics)
    agg_oute<<<(M + 1)/2, 256, 0, stream>>>(rg1, adj1, pk1, a1h, xlb, outeb,
                                            a2h, M);
    // 6. round 2 (stats fused, bound shift)
    agg_outn<<<(N + 3)/4, 256, 0, stream>>>(rg0, adj0, a2x, a2h, Dinv, outeb,
                                            (uint*)&ctrl[2], out, N);
}